// Round 5
// baseline (205.956 us; speedup 1.0000x reference)
//
#include <hip/hip_runtime.h>
#include <hip/hip_fp16.h>

// RNNT Joint: logits[b,t,u,c] = relu(f[b,t,:] + g[b,u,:]) . out_w[c,:] + out_b[c]
// f = enc_out @ enc_w^T + enc_b    [8,512,320]
// g = pred_out @ pred_w^T + pred_b [8,128,320]
// Sizes: B=8 T=512 U=128 E=768 P=320 H=320 C=34

typedef _Float16 f16x8 __attribute__((ext_vector_type(8)));
typedef __fp16   fp16x2 __attribute__((ext_vector_type(2)));
typedef float    f32x4 __attribute__((ext_vector_type(4)));
typedef int      i32x4 __attribute__((ext_vector_type(4)));

#define B_ 8
#define T_ 512
#define U_ 128
#define H_ 320
#define C_ 34

__device__ inline f16x8 pack8(f32x4 a, f32x4 b) {
    union { fp16x2 h[4]; f16x8 v; } u;
    u.h[0] = __builtin_amdgcn_cvt_pkrtz(a[0], a[1]);
    u.h[1] = __builtin_amdgcn_cvt_pkrtz(a[2], a[3]);
    u.h[2] = __builtin_amdgcn_cvt_pkrtz(b[0], b[1]);
    u.h[3] = __builtin_amdgcn_cvt_pkrtz(b[2], b[3]);
    return u.v;
}

// ---------------------------------------------------------------------------
// Fused projection GEMMs: Out[M][320] = A[M][K] * W[320][K]^T + bias, fp16 out.
// Blocks 0..319: enc (M=4096,K=768). Blocks 320..399: pred (M=1024,K=320).
// Tile 64x64, K-step 32, 4 waves (2x2 of 32x32), double-buffered LDS,
// register prefetch one K-step ahead -> ONE barrier per K-step.
// ---------------------------------------------------------------------------
__global__ __launch_bounds__(256, 4)
void proj_fused(const float* __restrict__ enc_out, const float* __restrict__ enc_w,
                const float* __restrict__ enc_b, const float* __restrict__ pred_out,
                const float* __restrict__ pred_w, const float* __restrict__ pred_b,
                _Float16* __restrict__ F, _Float16* __restrict__ G) {
    __shared__ _Float16 As[2][64 * 40];
    __shared__ _Float16 Ws[2][64 * 40];

    int blk = blockIdx.x;
    const float *A, *W, *bias;
    _Float16* Out;
    int K, mt, nt;
    if (blk < 320) {
        A = enc_out; W = enc_w; bias = enc_b; Out = F; K = 768;
        mt = blk & 63; nt = blk >> 6;
    } else {
        blk -= 320;
        A = pred_out; W = pred_w; bias = pred_b; Out = G; K = 320;
        mt = blk & 15; nt = blk >> 4;
    }
    const int bm = mt * 64;
    const int bn = nt * 64;

    const int tid = threadIdx.x;
    const int l   = tid & 63;
    const int w   = tid >> 6;
    const int wm  = (w >> 1) * 32;
    const int wn  = (w & 1) * 32;
    const int q   = l >> 4;      // 0..3 (k-slice group)
    const int r16 = l & 15;

    const int srow = tid >> 2;        // 0..63
    const int scol = (tid & 3) * 8;   // 0,8,16,24

    f32x4 acc[2][2] = {};

    const float* arow = A + (size_t)(bm + srow) * K + scol;
    const float* wrow = W + (size_t)(bn + srow) * K + scol;

    // prologue: prefetch K-step 0
    f32x4 a0 = *(const f32x4*)(arow);
    f32x4 a1 = *(const f32x4*)(arow + 4);
    f32x4 w0 = *(const f32x4*)(wrow);
    f32x4 w1 = *(const f32x4*)(wrow + 4);

    int p = 0;
    for (int k0 = 0; k0 < K; k0 += 32) {
        // pack + write LDS buf p
        *(f16x8*)&As[p][srow * 40 + scol] = pack8(a0, a1);
        *(f16x8*)&Ws[p][srow * 40 + scol] = pack8(w0, w1);

        // issue next K-step's global loads (latency hides under MFMA phase)
        if (k0 + 32 < K) {
            a0 = *(const f32x4*)(arow + k0 + 32);
            a1 = *(const f32x4*)(arow + k0 + 36);
            w0 = *(const f32x4*)(wrow + k0 + 32);
            w1 = *(const f32x4*)(wrow + k0 + 36);
        }

        __syncthreads();

        f16x8 afr0 = *(const f16x8*)&As[p][(wm + r16) * 40 + q * 8];
        f16x8 afr1 = *(const f16x8*)&As[p][(wm + 16 + r16) * 40 + q * 8];
        f16x8 bfr0 = *(const f16x8*)&Ws[p][(wn + r16) * 40 + q * 8];
        f16x8 bfr1 = *(const f16x8*)&Ws[p][(wn + 16 + r16) * 40 + q * 8];

        acc[0][0] = __builtin_amdgcn_mfma_f32_16x16x32_f16(afr0, bfr0, acc[0][0], 0, 0, 0);
        acc[0][1] = __builtin_amdgcn_mfma_f32_16x16x32_f16(afr0, bfr1, acc[0][1], 0, 0, 0);
        acc[1][0] = __builtin_amdgcn_mfma_f32_16x16x32_f16(afr1, bfr0, acc[1][0], 0, 0, 0);
        acc[1][1] = __builtin_amdgcn_mfma_f32_16x16x32_f16(afr1, bfr1, acc[1][1], 0, 0, 0);
        p ^= 1;
    }

    // Epilogue: C/D layout col = l&15, row = (l>>4)*4 + rr  [m89]
#pragma unroll
    for (int mrep = 0; mrep < 2; ++mrep) {
#pragma unroll
        for (int nrep = 0; nrep < 2; ++nrep) {
            int col  = bn + wn + nrep * 16 + r16;
            float bv = bias[col];
#pragma unroll
            for (int rr = 0; rr < 4; ++rr) {
                int row = bm + wm + mrep * 16 + q * 4 + rr;
                Out[(size_t)row * H_ + col] = (_Float16)(acc[mrep][nrep][rr] + bv);
            }
        }
    }
}

// ---------------------------------------------------------------------------
// Joint kernel: per block (t-chunk 16, u-tile 16, b). 4 waves, wave = 4 t's.
// 2048 blocks -> ~4 blocks/CU co-resident (16 waves/CU) for store concurrency.
// A-rows = 16 u's, K = H = 320 (10 steps of 32), 3 N-tiles of 16 (C padded 48).
// out_w converted fp32->fp16 in-kernel, held in registers; g-tile in LDS.
// ---------------------------------------------------------------------------
__global__ __launch_bounds__(256, 4)
void joint_kernel(const _Float16* __restrict__ F, const _Float16* __restrict__ G,
                  const float* __restrict__ out_w, const float* __restrict__ out_b,
                  float* __restrict__ out) {
    __shared__ _Float16 glds[16 * 328];  // stride 328: balanced banks for b128

    const int tid = threadIdx.x;
    const int l   = tid & 63;
    const int w   = tid >> 6;
    const int q   = l >> 4;    // 0..3
    const int r16 = l & 15;
    const int tc  = blockIdx.x;  // 0..31 (t-chunk of 16)
    const int ut  = blockIdx.y;  // 0..7 (u-tile of 16)
    const int b   = blockIdx.z;  // 0..7
    const int u0  = ut * 16;

    // stage g-tile [16][320] -> LDS
    {
        const _Float16* gsrc = G + ((size_t)b * U_ + u0) * H_;
        for (int i = tid; i < 16 * 40; i += 256) {  // 40 x 16B per row
            int row = i / 40;
            int c8  = (i - row * 40) * 8;
            *(i32x4*)&glds[row * 328 + c8] = *(const i32x4*)(gsrc + row * H_ + c8);
        }
    }

    // out_w fragments (loop-invariant), converted fp32->fp16 here; + bias
    f16x8 bfr[3][10];
    float ob[3];
#pragma unroll
    for (int nt = 0; nt < 3; ++nt) {
        const int n = nt * 16 + r16;  // class row (N=K-layout: [34 valid][320])
        const bool valid = (n < C_);
        const float* wr = out_w + (size_t)n * H_;
        ob[nt] = valid ? out_b[n] : 0.f;
#pragma unroll
        for (int s = 0; s < 10; ++s) {
            f16x8 v = {};
            if (valid) {
                f32x4 x0 = *(const f32x4*)(wr + s * 32 + q * 8);
                f32x4 x1 = *(const f32x4*)(wr + s * 32 + q * 8 + 4);
                v = pack8(x0, x1);
            }
            bfr[nt][s] = v;
        }
    }

    __syncthreads();

    const int tbase = tc * 16 + w * 4;
    for (int tt = 0; tt < 4; ++tt) {
        const int t = tbase + tt;
        const _Float16* frow = F + ((size_t)b * T_ + t) * H_;

        f32x4 acc0 = {}, acc1 = {}, acc2 = {};
#pragma unroll
        for (int s = 0; s < 10; ++s) {
            f16x8 fv = *(const f16x8*)(frow + s * 32 + q * 8);  // broadcast (16 lanes/addr)
            f16x8 gv = *(const f16x8*)&glds[r16 * 328 + s * 32 + q * 8];
            f16x8 jv = fv + gv;                     // 4x v_pk_add_f16
            const f16x8 fz = {};
            jv = __builtin_elementwise_max(jv, fz); // 4x v_pk_max_f16 (relu)
            acc0 = __builtin_amdgcn_mfma_f32_16x16x32_f16(jv, bfr[0][s], acc0, 0, 0, 0);
            acc1 = __builtin_amdgcn_mfma_f32_16x16x32_f16(jv, bfr[1][s], acc1, 0, 0, 0);
            acc2 = __builtin_amdgcn_mfma_f32_16x16x32_f16(jv, bfr[2][s], acc2, 0, 0, 0);
        }

        // store: row (u-offset) = q*4+rr, col (class) = nt*16 + r16
        float* orow = out + (((size_t)b * T_ + t) * U_ + u0) * C_;
#pragma unroll
        for (int rr = 0; rr < 4; ++rr) {
            const int m = q * 4 + rr;
            orow[m * C_ + r16]      = acc0[rr] + ob[0];
            orow[m * C_ + 16 + r16] = acc1[rr] + ob[1];
            if (r16 < 2)
                orow[m * C_ + 32 + r16] = acc2[rr] + ob[2];
        }
    }
}

// ---------------------------------------------------------------------------
extern "C" void kernel_launch(void* const* d_in, const int* in_sizes, int n_in,
                              void* d_out, int out_size, void* d_ws, size_t ws_size,
                              hipStream_t stream) {
    const float* enc_out  = (const float*)d_in[0];
    const float* pred_out = (const float*)d_in[1];
    const float* enc_w    = (const float*)d_in[2];
    const float* enc_b    = (const float*)d_in[3];
    const float* pred_w   = (const float*)d_in[4];
    const float* pred_b   = (const float*)d_in[5];
    const float* out_w    = (const float*)d_in[6];
    const float* out_b    = (const float*)d_in[7];
    float* out = (float*)d_out;

    char* ws = (char*)d_ws;
    _Float16* F = (_Float16*)ws;                            // 4096*320 fp16
    _Float16* G = (_Float16*)(ws + (size_t)4096 * 320 * 2); // 1024*320 fp16

    proj_fused<<<400, 256, 0, stream>>>(enc_out, enc_w, enc_b,
                                        pred_out, pred_w, pred_b, F, G);
    joint_kernel<<<dim3(32, 8, 8), 256, 0, stream>>>(F, G, out_w, out_b, out);
}

// Round 6
// 44.227 us; speedup vs baseline: 4.6568x; 4.6568x over previous
//
#include <hip/hip_runtime.h>
#include <hip/hip_fp16.h>

// RNNT Joint: logits[b,t,u,c] = relu(f[b,t,:] + g[b,u,:]) . out_w[c,:] + out_b[c]
// f = enc_out @ enc_w^T + enc_b    [8,512,320]
// g = pred_out @ pred_w^T + pred_b [8,128,320]
// Sizes: B=8 T=512 U=128 E=768 P=320 H=320 C=34

typedef _Float16 f16x8 __attribute__((ext_vector_type(8)));
typedef __fp16   fp16x2 __attribute__((ext_vector_type(2)));
typedef float    f32x4 __attribute__((ext_vector_type(4)));
typedef int      i32x4 __attribute__((ext_vector_type(4)));

#define B_ 8
#define T_ 512
#define U_ 128
#define H_ 320
#define C_ 34

__device__ inline f16x8 pack8(f32x4 a, f32x4 b) {
    union { fp16x2 h[4]; f16x8 v; } u;
    u.h[0] = __builtin_amdgcn_cvt_pkrtz(a[0], a[1]);
    u.h[1] = __builtin_amdgcn_cvt_pkrtz(a[2], a[3]);
    u.h[2] = __builtin_amdgcn_cvt_pkrtz(b[0], b[1]);
    u.h[3] = __builtin_amdgcn_cvt_pkrtz(b[2], b[3]);
    return u.v;
}

// ---------------------------------------------------------------------------
// Fused projection GEMMs: Out[M][320] = A[M][K] * W[320][K]^T + bias, fp16 out.
// Blocks 0..319: enc (M=4096,K=768). Blocks 320..399: pred (M=1024,K=320).
// Tile 64x64, K-step 32, 4 waves (2x2 of 32x32), double-buffered LDS,
// register prefetch one K-step ahead -> ONE barrier per K-step.  (proven R3)
// ---------------------------------------------------------------------------
__global__ __launch_bounds__(256, 4)
void proj_fused(const float* __restrict__ enc_out, const float* __restrict__ enc_w,
                const float* __restrict__ enc_b, const float* __restrict__ pred_out,
                const float* __restrict__ pred_w, const float* __restrict__ pred_b,
                _Float16* __restrict__ F, _Float16* __restrict__ G) {
    __shared__ _Float16 As[2][64 * 40];
    __shared__ _Float16 Ws[2][64 * 40];

    int blk = blockIdx.x;
    const float *A, *W, *bias;
    _Float16* Out;
    int K, mt, nt;
    if (blk < 320) {
        A = enc_out; W = enc_w; bias = enc_b; Out = F; K = 768;
        mt = blk & 63; nt = blk >> 6;
    } else {
        blk -= 320;
        A = pred_out; W = pred_w; bias = pred_b; Out = G; K = 320;
        mt = blk & 15; nt = blk >> 4;
    }
    const int bm = mt * 64;
    const int bn = nt * 64;

    const int tid = threadIdx.x;
    const int l   = tid & 63;
    const int w   = tid >> 6;
    const int wm  = (w >> 1) * 32;
    const int wn  = (w & 1) * 32;
    const int q   = l >> 4;      // 0..3 (k-slice group)
    const int r16 = l & 15;

    const int srow = tid >> 2;        // 0..63
    const int scol = (tid & 3) * 8;   // 0,8,16,24

    f32x4 acc[2][2] = {};

    const float* arow = A + (size_t)(bm + srow) * K + scol;
    const float* wrow = W + (size_t)(bn + srow) * K + scol;

    // prologue: prefetch K-step 0
    f32x4 a0 = *(const f32x4*)(arow);
    f32x4 a1 = *(const f32x4*)(arow + 4);
    f32x4 w0 = *(const f32x4*)(wrow);
    f32x4 w1 = *(const f32x4*)(wrow + 4);

    int p = 0;
    for (int k0 = 0; k0 < K; k0 += 32) {
        *(f16x8*)&As[p][srow * 40 + scol] = pack8(a0, a1);
        *(f16x8*)&Ws[p][srow * 40 + scol] = pack8(w0, w1);

        if (k0 + 32 < K) {  // next K-step's loads hide under MFMA phase
            a0 = *(const f32x4*)(arow + k0 + 32);
            a1 = *(const f32x4*)(arow + k0 + 36);
            w0 = *(const f32x4*)(wrow + k0 + 32);
            w1 = *(const f32x4*)(wrow + k0 + 36);
        }

        __syncthreads();

        f16x8 afr0 = *(const f16x8*)&As[p][(wm + r16) * 40 + q * 8];
        f16x8 afr1 = *(const f16x8*)&As[p][(wm + 16 + r16) * 40 + q * 8];
        f16x8 bfr0 = *(const f16x8*)&Ws[p][(wn + r16) * 40 + q * 8];
        f16x8 bfr1 = *(const f16x8*)&Ws[p][(wn + 16 + r16) * 40 + q * 8];

        acc[0][0] = __builtin_amdgcn_mfma_f32_16x16x32_f16(afr0, bfr0, acc[0][0], 0, 0, 0);
        acc[0][1] = __builtin_amdgcn_mfma_f32_16x16x32_f16(afr0, bfr1, acc[0][1], 0, 0, 0);
        acc[1][0] = __builtin_amdgcn_mfma_f32_16x16x32_f16(afr1, bfr0, acc[1][0], 0, 0, 0);
        acc[1][1] = __builtin_amdgcn_mfma_f32_16x16x32_f16(afr1, bfr1, acc[1][1], 0, 0, 0);
        p ^= 1;
    }

    // Epilogue: C/D layout col = l&15, row = (l>>4)*4 + rr  [m89]
#pragma unroll
    for (int mrep = 0; mrep < 2; ++mrep) {
#pragma unroll
        for (int nrep = 0; nrep < 2; ++nrep) {
            int col  = bn + wn + nrep * 16 + r16;
            float bv = bias[col];
#pragma unroll
            for (int rr = 0; rr < 4; ++rr) {
                int row = bm + wm + mrep * 16 + q * 4 + rr;
                Out[(size_t)row * H_ + col] = (_Float16)(acc[mrep][nrep][rr] + bv);
            }
        }
    }
}

// ---------------------------------------------------------------------------
// Joint kernel v2: per block (t-chunk 64, u-tile 16, b); 4 waves x 16 t's.
// Setup per block (cheap, coalesced):
//   - out_w fp32 -> fp16, XOR-swizzled LDS [48][320] (30 KB); each wave then
//     builds bfr[3][10] via 30 conflict-free ds_read_b128.
//   - g fragments (per-lane row u0+r16) loaded ONCE into registers (10 insts).
// t-loop: 10 broadcast F loads + packed add/relu + 30 MFMA + stores. No LDS.
// ---------------------------------------------------------------------------
__global__ __launch_bounds__(256, 2)
void joint_kernel(const _Float16* __restrict__ F, const _Float16* __restrict__ G,
                  const float* __restrict__ out_w, const float* __restrict__ out_b,
                  float* __restrict__ out) {
    __shared__ _Float16 owlds[48 * 320];  // 30720 B; row stride 640 B, XOR-swizzled

    const int tid = threadIdx.x;
    const int l   = tid & 63;
    const int w   = tid >> 6;
    const int q   = l >> 4;    // 0..3
    const int r16 = l & 15;
    const int tc  = blockIdx.x;  // 0..7 (t-chunk of 64)
    const int ut  = blockIdx.y;  // 0..7 (u-tile of 16)
    const int b   = blockIdx.z;  // 0..7
    const int u0  = ut * 16;

    char* ow = (char*)owlds;

    // stage out_w [34][320] fp32 -> fp16 swizzled LDS [48][320] (rows 34..47 = 0)
    for (int i = tid; i < 48 * 40; i += 256) {   // 1920 chunks of 8 f16
        int n  = i / 40;
        int c8 = (i - n * 40) * 8;               // f16 column
        f16x8 v = {};
        if (n < C_) {
            f32x4 x0 = *(const f32x4*)(out_w + n * H_ + c8);
            f32x4 x1 = *(const f32x4*)(out_w + n * H_ + c8 + 4);
            v = pack8(x0, x1);
        }
        *(f16x8*)(ow + n * 640 + ((c8 * 2) ^ ((n & 7) << 4))) = v;
    }

    // g fragments: per-lane row u0+r16, loop-invariant over t (A-operand)
    f16x8 gfr[10];
    {
        const _Float16* grow = G + ((size_t)b * U_ + u0 + r16) * H_;
#pragma unroll
        for (int s = 0; s < 10; ++s)
            gfr[s] = *(const f16x8*)(grow + s * 32 + q * 8);
    }

    float ob[3];
#pragma unroll
    for (int nt = 0; nt < 3; ++nt) {
        int n = nt * 16 + r16;
        ob[nt] = (n < C_) ? out_b[n] : 0.f;
    }

    __syncthreads();

    // B-fragments from swizzled LDS (conflict-free b128: 8 touches/bank = min)
    f16x8 bfr[3][10];
#pragma unroll
    for (int nt = 0; nt < 3; ++nt) {
        int n = nt * 16 + r16;
#pragma unroll
        for (int s = 0; s < 10; ++s)
            bfr[nt][s] = *(const f16x8*)(ow + n * 640 + ((s * 64 + q * 16) ^ ((n & 7) << 4)));
    }

    const int tbase = tc * 64 + w * 16;
    for (int tt = 0; tt < 16; ++tt) {
        const int t = tbase + tt;
        const _Float16* frow = F + ((size_t)b * T_ + t) * H_;

        f32x4 acc0 = {}, acc1 = {}, acc2 = {};
#pragma unroll
        for (int s = 0; s < 10; ++s) {
            f16x8 fv = *(const f16x8*)(frow + s * 32 + q * 8);  // 16-lane broadcast
            f16x8 jv = fv + gfr[s];                 // 4x v_pk_add_f16
            const f16x8 fz = {};
            jv = __builtin_elementwise_max(jv, fz); // 4x v_pk_max_f16 (relu)
            acc0 = __builtin_amdgcn_mfma_f32_16x16x32_f16(jv, bfr[0][s], acc0, 0, 0, 0);
            acc1 = __builtin_amdgcn_mfma_f32_16x16x32_f16(jv, bfr[1][s], acc1, 0, 0, 0);
            acc2 = __builtin_amdgcn_mfma_f32_16x16x32_f16(jv, bfr[2][s], acc2, 0, 0, 0);
        }

        // store: row (u-offset) = q*4+rr, col (class) = nt*16 + r16
        float* orow = out + (((size_t)b * T_ + t) * U_ + u0) * C_;
#pragma unroll
        for (int rr = 0; rr < 4; ++rr) {
            const int m = q * 4 + rr;
            orow[m * C_ + r16]      = acc0[rr] + ob[0];
            orow[m * C_ + 16 + r16] = acc1[rr] + ob[1];
            if (r16 < 2)
                orow[m * C_ + 32 + r16] = acc2[rr] + ob[2];
        }
    }
}

// ---------------------------------------------------------------------------
extern "C" void kernel_launch(void* const* d_in, const int* in_sizes, int n_in,
                              void* d_out, int out_size, void* d_ws, size_t ws_size,
                              hipStream_t stream) {
    const float* enc_out  = (const float*)d_in[0];
    const float* pred_out = (const float*)d_in[1];
    const float* enc_w    = (const float*)d_in[2];
    const float* enc_b    = (const float*)d_in[3];
    const float* pred_w   = (const float*)d_in[4];
    const float* pred_b   = (const float*)d_in[5];
    const float* out_w    = (const float*)d_in[6];
    const float* out_b    = (const float*)d_in[7];
    float* out = (float*)d_out;

    char* ws = (char*)d_ws;
    _Float16* F = (_Float16*)ws;                            // 4096*320 fp16
    _Float16* G = (_Float16*)(ws + (size_t)4096 * 320 * 2); // 1024*320 fp16

    proj_fused<<<400, 256, 0, stream>>>(enc_out, enc_w, enc_b,
                                        pred_out, pred_w, pred_b, F, G);
    joint_kernel<<<dim3(8, 8, 8), 256, 0, stream>>>(F, G, out_w, out_b, out);
}

// Round 7
// 43.501 us; speedup vs baseline: 4.7345x; 1.0167x over previous
//
#include <hip/hip_runtime.h>
#include <hip/hip_fp16.h>

// RNNT Joint: logits[b,t,u,c] = relu(f[b,t,:] + g[b,u,:]) . out_w[c,:] + out_b[c]
// f = enc_out @ enc_w^T + enc_b    [8,512,320]
// g = pred_out @ pred_w^T + pred_b [8,128,320]
// Sizes: B=8 T=512 U=128 E=768 P=320 H=320 C=34

typedef _Float16 f16x8 __attribute__((ext_vector_type(8)));
typedef _Float16 f16x4 __attribute__((ext_vector_type(4)));
typedef __fp16   fp16x2 __attribute__((ext_vector_type(2)));
typedef float    f32x4 __attribute__((ext_vector_type(4)));
typedef int      i32x4 __attribute__((ext_vector_type(4)));

#define B_ 8
#define T_ 512
#define U_ 128
#define H_ 320
#define C_ 34

__device__ inline f16x8 pack8(f32x4 a, f32x4 b) {
    union { fp16x2 h[4]; f16x8 v; } u;
    u.h[0] = __builtin_amdgcn_cvt_pkrtz(a[0], a[1]);
    u.h[1] = __builtin_amdgcn_cvt_pkrtz(a[2], a[3]);
    u.h[2] = __builtin_amdgcn_cvt_pkrtz(b[0], b[1]);
    u.h[3] = __builtin_amdgcn_cvt_pkrtz(b[2], b[3]);
    return u.v;
}

__device__ inline f16x4 pack4(f32x4 a) {
    union { fp16x2 h[2]; f16x4 v; } u;
    u.h[0] = __builtin_amdgcn_cvt_pkrtz(a[0], a[1]);
    u.h[1] = __builtin_amdgcn_cvt_pkrtz(a[2], a[3]);
    return u.v;
}

// ---------------------------------------------------------------------------
// Fused projection GEMMs: Out[M][320] = A[M][K] * W[320][K]^T + bias, fp16 out.
// Blocks 0..319: enc (M=4096,K=768). Blocks 320..399: pred (M=1024,K=320).
// Tile 64x64, 512 threads (8 waves, 2m x 4n, 32x16 each), K-step 32,
// double-buffered LDS, unroll-by-2 K-loop with 2-deep register prefetch,
// ONE barrier per K-step. 2 blocks/CU co-resident -> ~6 waves/SIMD with TLP.
// ---------------------------------------------------------------------------
__global__ __launch_bounds__(512, 4)
void proj_fused(const float* __restrict__ enc_out, const float* __restrict__ enc_w,
                const float* __restrict__ enc_b, const float* __restrict__ pred_out,
                const float* __restrict__ pred_w, const float* __restrict__ pred_b,
                _Float16* __restrict__ F, _Float16* __restrict__ G) {
    __shared__ _Float16 As[2][64 * 40];
    __shared__ _Float16 Ws[2][64 * 40];

    int blk = blockIdx.x;
    const float *A, *W, *bias;
    _Float16* Out;
    int K, mt, nt;
    if (blk < 320) {
        A = enc_out; W = enc_w; bias = enc_b; Out = F; K = 768;
        mt = blk & 63; nt = blk >> 6;
    } else {
        blk -= 320;
        A = pred_out; W = pred_w; bias = pred_b; Out = G; K = 320;
        mt = blk & 15; nt = blk >> 4;
    }
    const int bm = mt * 64;
    const int bn = nt * 64;

    const int tid = threadIdx.x;
    const int l   = tid & 63;
    const int w   = tid >> 6;          // 0..7
    const int wm  = (w >> 2) * 32;     // 0,32
    const int wn  = (w & 3) * 16;      // 0,16,32,48
    const int q   = l >> 4;            // 0..3 (k-slice group)
    const int r16 = l & 15;

    const int srow = tid >> 3;         // 0..63
    const int scol = (tid & 7) * 4;    // float col 0,4,...,28

    f32x4 acc[2] = {};

    const float* arow = A + (size_t)(bm + srow) * K + scol;
    const float* wrow = W + (size_t)(bn + srow) * K + scol;

    // 2-deep prologue: K-steps 0 and 32 in flight
    f32x4 aA = *(const f32x4*)(arow);
    f32x4 wA = *(const f32x4*)(wrow);
    f32x4 aB = *(const f32x4*)(arow + 32);
    f32x4 wB = *(const f32x4*)(wrow + 32);

    for (int k0 = 0; k0 < K; k0 += 64) {
        // ---- phase A (buffer 0, K-step k0) ----
        *(f16x4*)&As[0][srow * 40 + scol] = pack4(aA);
        *(f16x4*)&Ws[0][srow * 40 + scol] = pack4(wA);
        if (k0 + 64 < K) {
            aA = *(const f32x4*)(arow + k0 + 64);
            wA = *(const f32x4*)(wrow + k0 + 64);
        }
        __syncthreads();
        {
            f16x8 af0 = *(const f16x8*)&As[0][(wm + r16) * 40 + q * 8];
            f16x8 af1 = *(const f16x8*)&As[0][(wm + 16 + r16) * 40 + q * 8];
            f16x8 bf  = *(const f16x8*)&Ws[0][(wn + r16) * 40 + q * 8];
            acc[0] = __builtin_amdgcn_mfma_f32_16x16x32_f16(af0, bf, acc[0], 0, 0, 0);
            acc[1] = __builtin_amdgcn_mfma_f32_16x16x32_f16(af1, bf, acc[1], 0, 0, 0);
        }
        // ---- phase B (buffer 1, K-step k0+32) ----
        *(f16x4*)&As[1][srow * 40 + scol] = pack4(aB);
        *(f16x4*)&Ws[1][srow * 40 + scol] = pack4(wB);
        if (k0 + 96 < K) {
            aB = *(const f32x4*)(arow + k0 + 96);
            wB = *(const f32x4*)(wrow + k0 + 96);
        }
        __syncthreads();
        {
            f16x8 af0 = *(const f16x8*)&As[1][(wm + r16) * 40 + q * 8];
            f16x8 af1 = *(const f16x8*)&As[1][(wm + 16 + r16) * 40 + q * 8];
            f16x8 bf  = *(const f16x8*)&Ws[1][(wn + r16) * 40 + q * 8];
            acc[0] = __builtin_amdgcn_mfma_f32_16x16x32_f16(af0, bf, acc[0], 0, 0, 0);
            acc[1] = __builtin_amdgcn_mfma_f32_16x16x32_f16(af1, bf, acc[1], 0, 0, 0);
        }
    }

    // Epilogue: C/D layout col = l&15, row = (l>>4)*4 + rr  [m89]
    {
        int col  = bn + wn + r16;
        float bv = bias[col];
#pragma unroll
        for (int mrep = 0; mrep < 2; ++mrep) {
#pragma unroll
            for (int rr = 0; rr < 4; ++rr) {
                int row = bm + wm + mrep * 16 + q * 4 + rr;
                Out[(size_t)row * H_ + col] = (_Float16)(acc[mrep][rr] + bv);
            }
        }
    }
}

// ---------------------------------------------------------------------------
// Joint kernel v2 (proven R6): per block (t-chunk 64, u-tile 16, b); 4 waves.
// Setup: out_w fp32->fp16 XOR-swizzled LDS (coalesced), bfr via ds_read_b128;
// g fragments in registers. t-loop: broadcast F loads + pk add/relu + 30 MFMA.
// ---------------------------------------------------------------------------
__global__ __launch_bounds__(256, 2)
void joint_kernel(const _Float16* __restrict__ F, const _Float16* __restrict__ G,
                  const float* __restrict__ out_w, const float* __restrict__ out_b,
                  float* __restrict__ out) {
    __shared__ _Float16 owlds[48 * 320];  // 30720 B; row stride 640 B, XOR-swizzled

    const int tid = threadIdx.x;
    const int l   = tid & 63;
    const int w   = tid >> 6;
    const int q   = l >> 4;    // 0..3
    const int r16 = l & 15;
    const int tc  = blockIdx.x;  // 0..7 (t-chunk of 64)
    const int ut  = blockIdx.y;  // 0..7 (u-tile of 16)
    const int b   = blockIdx.z;  // 0..7
    const int u0  = ut * 16;

    char* ow = (char*)owlds;

    // stage out_w [34][320] fp32 -> fp16 swizzled LDS [48][320] (rows 34..47 = 0)
    for (int i = tid; i < 48 * 40; i += 256) {   // 1920 chunks of 8 f16
        int n  = i / 40;
        int c8 = (i - n * 40) * 8;               // f16 column
        f16x8 v = {};
        if (n < C_) {
            f32x4 x0 = *(const f32x4*)(out_w + n * H_ + c8);
            f32x4 x1 = *(const f32x4*)(out_w + n * H_ + c8 + 4);
            v = pack8(x0, x1);
        }
        *(f16x8*)(ow + n * 640 + ((c8 * 2) ^ ((n & 7) << 4))) = v;
    }

    // g fragments: per-lane row u0+r16, loop-invariant over t (A-operand)
    f16x8 gfr[10];
    {
        const _Float16* grow = G + ((size_t)b * U_ + u0 + r16) * H_;
#pragma unroll
        for (int s = 0; s < 10; ++s)
            gfr[s] = *(const f16x8*)(grow + s * 32 + q * 8);
    }

    float ob[3];
#pragma unroll
    for (int nt = 0; nt < 3; ++nt) {
        int n = nt * 16 + r16;
        ob[nt] = (n < C_) ? out_b[n] : 0.f;
    }

    __syncthreads();

    // B-fragments from swizzled LDS (conflict-free b128: 8 touches/bank = min)
    f16x8 bfr[3][10];
#pragma unroll
    for (int nt = 0; nt < 3; ++nt) {
        int n = nt * 16 + r16;
#pragma unroll
        for (int s = 0; s < 10; ++s)
            bfr[nt][s] = *(const f16x8*)(ow + n * 640 + ((s * 64 + q * 16) ^ ((n & 7) << 4)));
    }

    const int tbase = tc * 64 + w * 16;
    for (int tt = 0; tt < 16; ++tt) {
        const int t = tbase + tt;
        const _Float16* frow = F + ((size_t)b * T_ + t) * H_;

        f32x4 acc0 = {}, acc1 = {}, acc2 = {};
#pragma unroll
        for (int s = 0; s < 10; ++s) {
            f16x8 fv = *(const f16x8*)(frow + s * 32 + q * 8);  // 16-lane broadcast
            f16x8 jv = fv + gfr[s];                 // 4x v_pk_add_f16
            const f16x8 fz = {};
            jv = __builtin_elementwise_max(jv, fz); // 4x v_pk_max_f16 (relu)
            acc0 = __builtin_amdgcn_mfma_f32_16x16x32_f16(jv, bfr[0][s], acc0, 0, 0, 0);
            acc1 = __builtin_amdgcn_mfma_f32_16x16x32_f16(jv, bfr[1][s], acc1, 0, 0, 0);
            acc2 = __builtin_amdgcn_mfma_f32_16x16x32_f16(jv, bfr[2][s], acc2, 0, 0, 0);
        }

        // store: row (u-offset) = q*4+rr, col (class) = nt*16 + r16
        float* orow = out + (((size_t)b * T_ + t) * U_ + u0) * C_;
#pragma unroll
        for (int rr = 0; rr < 4; ++rr) {
            const int m = q * 4 + rr;
            orow[m * C_ + r16]      = acc0[rr] + ob[0];
            orow[m * C_ + 16 + r16] = acc1[rr] + ob[1];
            if (r16 < 2)
                orow[m * C_ + 32 + r16] = acc2[rr] + ob[2];
        }
    }
}

// ---------------------------------------------------------------------------
extern "C" void kernel_launch(void* const* d_in, const int* in_sizes, int n_in,
                              void* d_out, int out_size, void* d_ws, size_t ws_size,
                              hipStream_t stream) {
    const float* enc_out  = (const float*)d_in[0];
    const float* pred_out = (const float*)d_in[1];
    const float* enc_w    = (const float*)d_in[2];
    const float* enc_b    = (const float*)d_in[3];
    const float* pred_w   = (const float*)d_in[4];
    const float* pred_b   = (const float*)d_in[5];
    const float* out_w    = (const float*)d_in[6];
    const float* out_b    = (const float*)d_in[7];
    float* out = (float*)d_out;

    char* ws = (char*)d_ws;
    _Float16* F = (_Float16*)ws;                            // 4096*320 fp16
    _Float16* G = (_Float16*)(ws + (size_t)4096 * 320 * 2); // 1024*320 fp16

    proj_fused<<<400, 512, 0, stream>>>(enc_out, enc_w, enc_b,
                                        pred_out, pred_w, pred_b, F, G);
    joint_kernel<<<dim3(8, 8, 8), 256, 0, stream>>>(F, G, out_w, out_b, out);
}